// Round 6
// baseline (207.440 us; speedup 1.0000x reference)
//
#include <hip/hip_runtime.h>
#include <math.h>

#define SEQ 4096
#define DIM 1024
#define DHEAD 256
#define NHEADS 4

typedef __attribute__((ext_vector_type(8))) short bf16x8;
typedef __attribute__((ext_vector_type(4))) float f32x4;
typedef __attribute__((ext_vector_type(4))) short short4v;
typedef __attribute__((ext_vector_type(8))) short short8v;

// fp32 -> bf16 round-to-nearest-even, as raw ushort bits
__device__ __forceinline__ unsigned short f2b(float f) {
    union { float f; unsigned u; } v; v.f = f;
    unsigned r = v.u + 0x7FFFu + ((v.u >> 16) & 1u);
    return (unsigned short)(r >> 16);
}
__device__ __forceinline__ float b2f(unsigned short u) {
    union { unsigned u; float f; } v; v.u = ((unsigned)u) << 16;
    return v.f;
}

// async global->LDS, 16B per lane; lds = wave-uniform base, g is per-lane
__device__ __forceinline__ void gll16(const void* g, void* lds) {
    __builtin_amdgcn_global_load_lds(
        (const __attribute__((address_space(1))) unsigned*)g,
        (__attribute__((address_space(3))) unsigned*)lds, 16, 0, 0);
}

__device__ __forceinline__ f32x4 mfma16(bf16x8 a, bf16x8 b, f32x4 c) {
    return __builtin_amdgcn_mfma_f32_16x16x32_bf16(a, b, c, 0, 0, 0);
}

// ---------------------------------------------------------------------------
// convert fp32 -> bf16, n4 float4's
// ---------------------------------------------------------------------------
__global__ __launch_bounds__(256)
void conv_kernel(const float* __restrict__ in, unsigned short* __restrict__ out, int n4) {
    int i = blockIdx.x * 256 + threadIdx.x;
    if (i >= n4) return;
    float4 v = ((const float4*)in)[i];
    short4v o;
    o[0] = (short)f2b(v.x); o[1] = (short)f2b(v.y);
    o[2] = (short)f2b(v.z); o[3] = (short)f2b(v.w);
    *(short4v*)(out + (size_t)i * 4) = o;
}

// ---------------------------------------------------------------------------
// Wq [4][1024][256] fp32 -> WqT [4][256][1024] bf16
// ---------------------------------------------------------------------------
__global__ __launch_bounds__(256)
void wqt_kernel(const float* __restrict__ Wq, unsigned short* __restrict__ WqT) {
    __shared__ unsigned short T[64][72];
    const int tid = threadIdx.x;
    const int h = blockIdx.z;
    const int d0 = blockIdx.x * 64, c0 = blockIdx.y * 64;
#pragma unroll
    for (int it = 0; it < 4; ++it) {
        int f = tid + 256 * it;
        int row = f >> 4, cg = f & 15;
        float4 v = *(const float4*)&Wq[((size_t)(h * DIM + d0 + row)) * DHEAD + c0 + cg * 4];
        T[row][cg * 4 + 0] = f2b(v.x); T[row][cg * 4 + 1] = f2b(v.y);
        T[row][cg * 4 + 2] = f2b(v.z); T[row][cg * 4 + 3] = f2b(v.w);
    }
    __syncthreads();
#pragma unroll
    for (int it = 0; it < 2; ++it) {
        int f = tid + 256 * it;
        int cl = f >> 3, dg = f & 7;
        short8v o;
#pragma unroll
        for (int e = 0; e < 8; ++e) o[e] = (short)T[dg * 8 + e][cl];
        *(short8v*)&WqT[((size_t)(h * DHEAD + c0 + cl)) * DIM + d0 + dg * 8] = o;
    }
}

// ---------------------------------------------------------------------------
// qkv [4][4096][256] bf16 -> qkvT [4][256][4096] bf16
// ---------------------------------------------------------------------------
__global__ __launch_bounds__(256)
void qkvt_kernel(const unsigned short* __restrict__ qkv, unsigned short* __restrict__ qkvT) {
    __shared__ unsigned short T[64][72];
    const int tid = threadIdx.x;
    const int h = blockIdx.z;
    const int r0 = blockIdx.x * 64, c0 = blockIdx.y * 64;
#pragma unroll
    for (int it = 0; it < 2; ++it) {
        int f = tid + 256 * it;
        int row = f >> 3, cg = f & 7;
        short8v v = *(const short8v*)&qkv[((size_t)h * SEQ + r0 + row) * DHEAD + c0 + cg * 8];
#pragma unroll
        for (int e = 0; e < 8; ++e) T[row][cg * 8 + e] = (unsigned short)v[e];
    }
    __syncthreads();
#pragma unroll
    for (int it = 0; it < 2; ++it) {
        int f = tid + 256 * it;
        int cl = f >> 3, rg = f & 7;
        short8v o;
#pragma unroll
        for (int e = 0; e < 8; ++e) o[e] = (short)T[rg * 8 + e][cl];
        *(short8v*)&qkvT[((size_t)h * DHEAD + c0 + cl) * SEQ + r0 + rg * 8] = o;
    }
}

// ---------------------------------------------------------------------------
// K1: qkv = x @ Wq  (bf16 MFMA, BM=BN=128, BK=64, out: qkv bf16 [4][4096][256])
// ---------------------------------------------------------------------------
__global__ __launch_bounds__(256)
void qkv_gemm_kernel(const unsigned short* __restrict__ A,
                     const unsigned short* __restrict__ B,
                     unsigned short* __restrict__ qkv) {
    __shared__ unsigned short As[128 * 64];
    __shared__ unsigned short Bs[128 * 64];
    const int tid = threadIdx.x, w = tid >> 6, l = tid & 63;
    const int g = l >> 4, r16 = l & 15;
    const int m0 = blockIdx.x * 128, n0 = blockIdx.y * 128;
    const int wm = (w >> 1) * 64, wn = (w & 1) * 64;

    f32x4 acc[4][4];
#pragma unroll
    for (int mr = 0; mr < 4; ++mr)
#pragma unroll
        for (int nr = 0; nr < 4; ++nr) acc[mr][nr] = (f32x4){0.f, 0.f, 0.f, 0.f};

    for (int kb = 0; kb < DIM; kb += 64) {
        __syncthreads();
#pragma unroll
        for (int cc = 0; cc < 4; ++cc) {
            int row = w * 32 + cc * 8 + (l >> 3);
            int c = (l & 7) ^ (row & 7);
            gll16(&A[(size_t)(m0 + row) * DIM + kb + c * 8], &As[(size_t)(w * 32 + cc * 8) * 64]);
            gll16(&B[(size_t)(n0 + row) * DIM + kb + c * 8], &Bs[(size_t)(w * 32 + cc * 8) * 64]);
        }
        __syncthreads();
#pragma unroll
        for (int s = 0; s < 2; ++s) {
            bf16x8 af[4], bf[4];
#pragma unroll
            for (int mr = 0; mr < 4; ++mr) {
                int row = wm + mr * 16 + r16;
                int st = (s * 4 + g) ^ (row & 7);
                af[mr] = *(const bf16x8*)&As[row * 64 + st * 8];
            }
#pragma unroll
            for (int nr = 0; nr < 4; ++nr) {
                int row = wn + nr * 16 + r16;
                int st = (s * 4 + g) ^ (row & 7);
                bf[nr] = *(const bf16x8*)&Bs[row * 64 + st * 8];
            }
#pragma unroll
            for (int mr = 0; mr < 4; ++mr)
#pragma unroll
                for (int nr = 0; nr < 4; ++nr)
                    acc[mr][nr] = mfma16(af[mr], bf[nr], acc[mr][nr]);
        }
    }
#pragma unroll
    for (int mr = 0; mr < 4; ++mr)
#pragma unroll
        for (int nr = 0; nr < 4; ++nr) {
            int n = n0 + wn + nr * 16 + r16;
            int h = n >> 8, c = n & 255;
#pragma unroll
            for (int r = 0; r < 4; ++r) {
                int m = m0 + wm + mr * 16 + g * 4 + r;
                qkv[((size_t)h * SEQ + m) * DHEAD + c] = f2b(acc[mr][nr][r]);
            }
        }
}

// ---------------------------------------------------------------------------
// K2: MFMA flash attention. grid 256 (1 block/CU): bid&7 = (head<<1)|half
// (XCD-pins each (head,half) K/V stream), bid>>3 = q-block of 128 rows.
// 4 waves; wave w owns q-rows [qb*128+w*32, +32) END-TO-END (2 subtiles).
// Swapped QK^T (proven) -> lane-local softmax; PV per-wave via intra-wave
// Ps LDS round-trip (no barrier, lgkmcnt only). K + V^T double-buffered,
// prefetched one full iteration ahead; ONE __syncthreads per iter.
// ---------------------------------------------------------------------------
__global__ __launch_bounds__(256, 1)
void attn_kernel(const unsigned short* __restrict__ qkv,
                 const unsigned short* __restrict__ qkvT,
                 unsigned short* __restrict__ p0,
                 unsigned short* __restrict__ p1,
                 float* __restrict__ ml) {
    __shared__ unsigned short Ks[2][64 * 256];  // [j][d], chunk st=(c&24)|((c&7)^(j&7))
    __shared__ unsigned short Vt[2][256 * 64];  // [d][j], chunk st=c^(d&7)
    __shared__ unsigned short Ps[4][32 * 64];   // per-wave [q][j], chunk st=c^(q&7)

    const int tid = threadIdx.x, w = tid >> 6, l = tid & 63;
    const int g = l >> 4, r16 = l & 15;
    const int bid = blockIdx.x;
    const int h = (bid & 7) >> 1, hf = bid & 1;
    const int qb = bid >> 3;                     // 0..31
    const unsigned short* __restrict__ qh = qkv + (size_t)h * SEQ * DHEAD;
    const unsigned short* __restrict__ qth = qkvT + (size_t)h * DHEAD * SEQ;
    const int jb0 = hf * (SEQ / 2);
    const int NT = (SEQ / 2) / 64;               // 32 key tiles

    // Q frags (B-operand): q-row = qb*128 + w*32 + qs*16 + r16, d = 32s+8g+e
    bf16x8 qf[2][8];
#pragma unroll
    for (int qs = 0; qs < 2; ++qs) {
        const unsigned short* qrow =
            qh + (size_t)(qb * 128 + w * 32 + qs * 16 + r16) * DHEAD + g * 8;
#pragma unroll
        for (int s = 0; s < 8; ++s) qf[qs][s] = *(const bf16x8*)(qrow + s * 32);
    }

#define STAGEKV(buf, jb)                                                            \
    {                                                                               \
        _Pragma("unroll")                                                           \
        for (int cc = 0; cc < 8; ++cc) {                                            \
            int ch = w * 8 + cc;                                                    \
            int j = ch * 2 + (l >> 5);                                              \
            int cp = l & 31;                                                        \
            int c = (cp & 24) | ((cp & 7) ^ (j & 7));                               \
            gll16(&qh[(size_t)((jb) + j) * DHEAD + c * 8], &Ks[buf][(size_t)ch * 512]); \
        }                                                                           \
        _Pragma("unroll")                                                           \
        for (int cc = 0; cc < 8; ++cc) {                                            \
            int ch = w * 8 + cc;                                                    \
            int d = ch * 8 + (l >> 3);                                              \
            int c = (l & 7) ^ (d & 7);                                              \
            gll16(&qth[(size_t)d * SEQ + (jb) + c * 8], &Vt[buf][(size_t)ch * 512]); \
        }                                                                           \
    }

    STAGEKV(0, jb0);

    f32x4 Oacc[2][16];  // [qs][dt]: lane holds O[q=qs*16+4g+r][d=16dt+r16]
#pragma unroll
    for (int qs = 0; qs < 2; ++qs)
#pragma unroll
        for (int dt = 0; dt < 16; ++dt) Oacc[qs][dt] = (f32x4){0.f, 0.f, 0.f, 0.f};
    float mrow[2] = {-INFINITY, -INFINITY}, lrow[2] = {0.f, 0.f};  // q = qs*16+r16

    for (int t = 0; t < NT; ++t) {
        const int cur = t & 1;
        __syncthreads();   // drains vmcnt: buf[cur] landed; all waves done with buf[cur^1]
        if (t + 1 < NT) STAGEKV(cur ^ 1, jb0 + (t + 1) * 64);

        // ---- S^T = K @ Q^T: sacc[qs][jt][r] = S[q=qs*16+r16][j=16jt+4g+r] ----
        const unsigned short* Kb = &Ks[cur][0];
        f32x4 sacc[2][4];
#pragma unroll
        for (int qs = 0; qs < 2; ++qs)
#pragma unroll
            for (int jt = 0; jt < 4; ++jt) sacc[qs][jt] = (f32x4){0.f, 0.f, 0.f, 0.f};
        __builtin_amdgcn_s_setprio(1);
#pragma unroll
        for (int s = 0; s < 8; ++s)
#pragma unroll
            for (int jt = 0; jt < 4; ++jt) {
                int j = jt * 16 + r16;
                int c = s * 4 + g;
                int st = (c & 24) | ((c & 7) ^ (j & 7));
                bf16x8 af = *(const bf16x8*)&Kb[j * 256 + st * 8];
                sacc[0][jt] = mfma16(af, qf[0][s], sacc[0][jt]);
                sacc[1][jt] = mfma16(af, qf[1][s], sacc[1][jt]);
            }
        __builtin_amdgcn_s_setprio(0);

        // ---- softmax per qs (lane-local row), defer-rescale THR=8 ----
#pragma unroll
        for (int qs = 0; qs < 2; ++qs) {
            float mx = sacc[qs][0][0];
#pragma unroll
            for (int jt = 0; jt < 4; ++jt)
#pragma unroll
                for (int r = 0; r < 4; ++r) mx = fmaxf(mx, sacc[qs][jt][r]);
            mx = fmaxf(mx, __shfl_xor(mx, 16, 64));
            mx = fmaxf(mx, __shfl_xor(mx, 32, 64));

            bool needr = !__all(mx <= mrow[qs] + 8.f);
            float alpha = 1.f;
            if (needr) {
                float mn = fmaxf(mrow[qs], mx);
                alpha = __expf(mrow[qs] - mn);
                mrow[qs] = mn;
            }

            float rsum = 0.f;
            short4v pf[4];
#pragma unroll
            for (int jt = 0; jt < 4; ++jt)
#pragma unroll
                for (int r = 0; r < 4; ++r) {
                    float p = __expf(sacc[qs][jt][r] - mrow[qs]);
                    rsum += p;
                    pf[jt][r] = (short)f2b(p);
                }
            rsum += __shfl_xor(rsum, 16, 64);
            rsum += __shfl_xor(rsum, 32, 64);
            lrow[qs] = lrow[qs] * alpha + rsum;

            // P -> own-wave Ps: row = qs*16+r16, j0 = 16jt+4g (b64)
#pragma unroll
            for (int jt = 0; jt < 4; ++jt) {
                int st = (2 * jt + (g >> 1)) ^ (r16 & 7);
                *(short4v*)&Ps[w][(qs * 16 + r16) * 64 + st * 8 + (g & 1) * 4] = pf[jt];
            }

            if (needr) {
                float av[4];
#pragma unroll
                for (int r = 0; r < 4; ++r) av[r] = __shfl(alpha, 4 * g + r, 64);
#pragma unroll
                for (int dt = 0; dt < 16; ++dt)
#pragma unroll
                    for (int r = 0; r < 4; ++r) Oacc[qs][dt][r] *= av[r];
            }
        }

        // ---- intra-wave fence: Ps writes visible to own-wave reads ----
        asm volatile("s_waitcnt lgkmcnt(0)" ::: "memory");
        __builtin_amdgcn_sched_barrier(0);

        // ---- PA frags: A[q-row=r16][k=j=32s2+8g+e] from own Ps ----
        bf16x8 pa[2][2];
#pragma unroll
        for (int qs = 0; qs < 2; ++qs)
#pragma unroll
            for (int s2 = 0; s2 < 2; ++s2) {
                int st = (4 * s2 + g) ^ (r16 & 7);
                pa[qs][s2] = *(const bf16x8*)&Ps[w][(qs * 16 + r16) * 64 + st * 8];
            }

        // ---- O += P @ V: all 256 d per wave, V-frags reused across qs ----
        const unsigned short* Vb = &Vt[cur][0];
        __builtin_amdgcn_s_setprio(1);
#pragma unroll
        for (int dt = 0; dt < 16; ++dt) {
            int d = dt * 16 + r16;
#pragma unroll
            for (int s2 = 0; s2 < 2; ++s2) {
                int st = (4 * s2 + g) ^ (r16 & 7);
                bf16x8 bv = *(const bf16x8*)&Vb[d * 64 + st * 8];
                Oacc[0][dt] = mfma16(pa[0][s2], bv, Oacc[0][dt]);
                Oacc[1][dt] = mfma16(pa[1][s2], bv, Oacc[1][dt]);
            }
        }
        __builtin_amdgcn_s_setprio(0);
    }
#undef STAGEKV

    asm volatile("s_waitcnt vmcnt(0)" ::: "memory");

    // ---- epilogue: unnormalized partial O (bf16) + per-row (m, l) ----
    unsigned short* po = hf ? p1 : p0;
#pragma unroll
    for (int qs = 0; qs < 2; ++qs)
#pragma unroll
        for (int dt = 0; dt < 16; ++dt) {
            int d = dt * 16 + r16;
#pragma unroll
            for (int r = 0; r < 4; ++r) {
                int q = qb * 128 + w * 32 + qs * 16 + 4 * g + r;
                po[(size_t)q * (NHEADS * DHEAD) + h * DHEAD + d] = f2b(Oacc[qs][dt][r]);
            }
        }
    if (g == 0) {
#pragma unroll
        for (int qs = 0; qs < 2; ++qs) {
            int q = qb * 128 + w * 32 + qs * 16 + r16;
            float* mlq = ml + ((size_t)(hf * NHEADS + h) * SEQ + q) * 2;
            mlq[0] = mrow[qs]; mlq[1] = lrow[qs];
        }
    }
}

// ---------------------------------------------------------------------------
// K2b: combine the two key-halves:
// out = (e0*acc0 + e1*acc1) / (e0*l0 + e1*l1),  e_i = exp(m_i - max(m0,m1))
// ---------------------------------------------------------------------------
__global__ __launch_bounds__(256)
void combine_kernel(const unsigned short* __restrict__ pa,
                    const unsigned short* __restrict__ pb,
                    const float* __restrict__ ml,
                    unsigned short* __restrict__ zc) {
    size_t t = (size_t)blockIdx.x * 256 + threadIdx.x;
    size_t f = t * 8;
    int q = (int)(f >> 10);
    int h = (int)((f >> 8) & 3);
    const float* ml0 = ml + ((size_t)h * SEQ + q) * 2;
    const float* ml1 = ml + ((size_t)(NHEADS + h) * SEQ + q) * 2;
    float m0 = ml0[0], l0 = ml0[1], m1 = ml1[0], l1 = ml1[1];
    float M = fmaxf(m0, m1);
    float e0 = __expf(m0 - M), e1 = __expf(m1 - M);
    float inv = 1.f / (e0 * l0 + e1 * l1);
    e0 *= inv; e1 *= inv;
    short8v a = *(const short8v*)(pa + f);
    short8v b = *(const short8v*)(pb + f);
    short8v o;
#pragma unroll
    for (int e = 0; e < 8; ++e)
        o[e] = (short)f2b(e0 * b2f((unsigned short)a[e]) + e1 * b2f((unsigned short)b[e]));
    *(short8v*)(zc + f) = o;
}

// ---------------------------------------------------------------------------
// K3: out = zc @ lin_w^T + lin_b  (fp32 out + bias)
// ---------------------------------------------------------------------------
__global__ __launch_bounds__(256)
void out_gemm_kernel(const unsigned short* __restrict__ A,
                     const unsigned short* __restrict__ B,
                     const float* __restrict__ lb, float* __restrict__ out) {
    __shared__ unsigned short As[128 * 64];
    __shared__ unsigned short Bs[128 * 64];
    const int tid = threadIdx.x, w = tid >> 6, l = tid & 63;
    const int g = l >> 4, r16 = l & 15;
    const int m0 = blockIdx.x * 128, n0 = blockIdx.y * 128;
    const int wm = (w >> 1) * 64, wn = (w & 1) * 64;

    f32x4 acc[4][4];
#pragma unroll
    for (int mr = 0; mr < 4; ++mr)
#pragma unroll
        for (int nr = 0; nr < 4; ++nr) acc[mr][nr] = (f32x4){0.f, 0.f, 0.f, 0.f};

    for (int kb = 0; kb < DIM; kb += 64) {
        __syncthreads();
#pragma unroll
        for (int cc = 0; cc < 4; ++cc) {
            int row = w * 32 + cc * 8 + (l >> 3);
            int c = (l & 7) ^ (row & 7);
            gll16(&A[(size_t)(m0 + row) * DIM + kb + c * 8], &As[(size_t)(w * 32 + cc * 8) * 64]);
            gll16(&B[(size_t)(n0 + row) * DIM + kb + c * 8], &Bs[(size_t)(w * 32 + cc * 8) * 64]);
        }
        __syncthreads();
#pragma unroll
        for (int s = 0; s < 2; ++s) {
            bf16x8 af[4], bf[4];
#pragma unroll
            for (int mr = 0; mr < 4; ++mr) {
                int row = wm + mr * 16 + r16;
                int st = (s * 4 + g) ^ (row & 7);
                af[mr] = *(const bf16x8*)&As[row * 64 + st * 8];
            }
#pragma unroll
            for (int nr = 0; nr < 4; ++nr) {
                int row = wn + nr * 16 + r16;
                int st = (s * 4 + g) ^ (row & 7);
                bf[nr] = *(const bf16x8*)&Bs[row * 64 + st * 8];
            }
#pragma unroll
            for (int mr = 0; mr < 4; ++mr)
#pragma unroll
                for (int nr = 0; nr < 4; ++nr)
                    acc[mr][nr] = mfma16(af[mr], bf[nr], acc[mr][nr]);
        }
    }
#pragma unroll
    for (int mr = 0; mr < 4; ++mr)
#pragma unroll
        for (int nr = 0; nr < 4; ++nr) {
            int n = n0 + wn + nr * 16 + r16;
            float bv = lb[n];
#pragma unroll
            for (int r = 0; r < 4; ++r) {
                int m = m0 + wm + mr * 16 + g * 4 + r;
                out[(size_t)m * DIM + n] = acc[mr][nr][r] + bv;
            }
        }
}

// ---------------------------------------------------------------------------
extern "C" void kernel_launch(void* const* d_in, const int* in_sizes, int n_in,
                              void* d_out, int out_size, void* d_ws, size_t ws_size,
                              hipStream_t stream) {
    const float* x  = (const float*)d_in[0];   // [4096,1024]
    const float* Wq = (const float*)d_in[1];   // [4,1024,256]
    const float* lw = (const float*)d_in[2];   // [1024,1024]
    const float* lb = (const float*)d_in[3];   // [1024]
    float* out = (float*)d_out;                // [4096,1024] fp32

    char* wsb = (char*)d_ws;
    unsigned short* qkvb = (unsigned short*)(wsb);                      // [0,8)MB  [4][4096][256]
    unsigned short* qkvT = (unsigned short*)(wsb + ((size_t)8 << 20));  // [8,16)   [4][256][4096]
    unsigned short* xb   = (unsigned short*)(wsb + ((size_t)16 << 20)); // [16,24)  x bf16 -> p0/zc
    unsigned short* p0   = xb;                                          //          (post qkv_gemm)
    unsigned short* WqT  = (unsigned short*)(wsb + ((size_t)24 << 20)); // [24,26)  WqT bf16
    float*          ml   = (float*)(wsb + ((size_t)24 << 20));          //          reused post qkv_gemm
    unsigned short* lwb  = (unsigned short*)(wsb + ((size_t)26 << 20)); // [26,28)  lin_w bf16
    unsigned short* p1   = (unsigned short*)d_out;  // half-1 partial parks in d_out
                                                    // (dead until out_gemm, which runs last)

    conv_kernel<<<4096, 256, 0, stream>>>(x, xb, (SEQ * DIM) / 4);
    conv_kernel<<<1024, 256, 0, stream>>>(lw, lwb, (DIM * DIM) / 4);
    wqt_kernel<<<dim3(16, 4, 4), 256, 0, stream>>>(Wq, WqT);
    qkv_gemm_kernel<<<dim3(SEQ / 128, DIM / 128), 256, 0, stream>>>(xb, WqT, qkvb);
    qkvt_kernel<<<dim3(64, 4, 4), 256, 0, stream>>>(qkvb, qkvT);
    attn_kernel<<<256, 256, 0, stream>>>(qkvb, qkvT, p0, p1, ml);
    combine_kernel<<<(SEQ * DIM / 8) / 256, 256, 0, stream>>>(p0, p1, ml, p0);
    out_gemm_kernel<<<dim3(SEQ / 128, DIM / 128), 256, 0, stream>>>(p0, lwb, lb, out);
}

// Round 7
// 195.224 us; speedup vs baseline: 1.0626x; 1.0626x over previous
//
#include <hip/hip_runtime.h>
#include <math.h>

#define SEQ 4096
#define DIM 1024
#define DHEAD 256
#define NHEADS 4

typedef __attribute__((ext_vector_type(8))) short bf16x8;
typedef __attribute__((ext_vector_type(4))) float f32x4;
typedef __attribute__((ext_vector_type(4))) short short4v;
typedef __attribute__((ext_vector_type(8))) short short8v;

// fp32 -> bf16 round-to-nearest-even, as raw ushort bits
__device__ __forceinline__ unsigned short f2b(float f) {
    union { float f; unsigned u; } v; v.f = f;
    unsigned r = v.u + 0x7FFFu + ((v.u >> 16) & 1u);
    return (unsigned short)(r >> 16);
}
__device__ __forceinline__ float b2f(unsigned short u) {
    union { unsigned u; float f; } v; v.u = ((unsigned)u) << 16;
    return v.f;
}

// async global->LDS, 16B per lane; lds = wave-uniform base, g is per-lane
__device__ __forceinline__ void gll16(const void* g, void* lds) {
    __builtin_amdgcn_global_load_lds(
        (const __attribute__((address_space(1))) unsigned*)g,
        (__attribute__((address_space(3))) unsigned*)lds, 16, 0, 0);
}

__device__ __forceinline__ f32x4 mfma16(bf16x8 a, bf16x8 b, f32x4 c) {
    return __builtin_amdgcn_mfma_f32_16x16x32_bf16(a, b, c, 0, 0, 0);
}

// ---------------------------------------------------------------------------
// convert fp32 -> bf16, n4 float4's
// ---------------------------------------------------------------------------
__global__ __launch_bounds__(256)
void conv_kernel(const float* __restrict__ in, unsigned short* __restrict__ out, int n4) {
    int i = blockIdx.x * 256 + threadIdx.x;
    if (i >= n4) return;
    float4 v = ((const float4*)in)[i];
    short4v o;
    o[0] = (short)f2b(v.x); o[1] = (short)f2b(v.y);
    o[2] = (short)f2b(v.z); o[3] = (short)f2b(v.w);
    *(short4v*)(out + (size_t)i * 4) = o;
}

// ---------------------------------------------------------------------------
// Wq [4][1024][256] fp32 -> WqT [4][256][1024] bf16
// ---------------------------------------------------------------------------
__global__ __launch_bounds__(256)
void wqt_kernel(const float* __restrict__ Wq, unsigned short* __restrict__ WqT) {
    __shared__ unsigned short T[64][72];
    const int tid = threadIdx.x;
    const int h = blockIdx.z;
    const int d0 = blockIdx.x * 64, c0 = blockIdx.y * 64;
#pragma unroll
    for (int it = 0; it < 4; ++it) {
        int f = tid + 256 * it;
        int row = f >> 4, cg = f & 15;
        float4 v = *(const float4*)&Wq[((size_t)(h * DIM + d0 + row)) * DHEAD + c0 + cg * 4];
        T[row][cg * 4 + 0] = f2b(v.x); T[row][cg * 4 + 1] = f2b(v.y);
        T[row][cg * 4 + 2] = f2b(v.z); T[row][cg * 4 + 3] = f2b(v.w);
    }
    __syncthreads();
#pragma unroll
    for (int it = 0; it < 2; ++it) {
        int f = tid + 256 * it;
        int cl = f >> 3, dg = f & 7;
        short8v o;
#pragma unroll
        for (int e = 0; e < 8; ++e) o[e] = (short)T[dg * 8 + e][cl];
        *(short8v*)&WqT[((size_t)(h * DHEAD + c0 + cl)) * DIM + d0 + dg * 8] = o;
    }
}

// ---------------------------------------------------------------------------
// qkv [4][4096][256] bf16 -> qkvT [4][256][4096] bf16
// ---------------------------------------------------------------------------
__global__ __launch_bounds__(256)
void qkvt_kernel(const unsigned short* __restrict__ qkv, unsigned short* __restrict__ qkvT) {
    __shared__ unsigned short T[64][72];
    const int tid = threadIdx.x;
    const int h = blockIdx.z;
    const int r0 = blockIdx.x * 64, c0 = blockIdx.y * 64;
#pragma unroll
    for (int it = 0; it < 2; ++it) {
        int f = tid + 256 * it;
        int row = f >> 3, cg = f & 7;
        short8v v = *(const short8v*)&qkv[((size_t)h * SEQ + r0 + row) * DHEAD + c0 + cg * 8];
#pragma unroll
        for (int e = 0; e < 8; ++e) T[row][cg * 8 + e] = (unsigned short)v[e];
    }
    __syncthreads();
#pragma unroll
    for (int it = 0; it < 2; ++it) {
        int f = tid + 256 * it;
        int cl = f >> 3, rg = f & 7;
        short8v o;
#pragma unroll
        for (int e = 0; e < 8; ++e) o[e] = (short)T[rg * 8 + e][cl];
        *(short8v*)&qkvT[((size_t)h * DHEAD + c0 + cl) * SEQ + r0 + rg * 8] = o;
    }
}

// ---------------------------------------------------------------------------
// K1: qkv = x @ Wq  (bf16 MFMA, BM=BN=128, BK=64, out: qkv bf16 [4][4096][256])
// ---------------------------------------------------------------------------
__global__ __launch_bounds__(256)
void qkv_gemm_kernel(const unsigned short* __restrict__ A,
                     const unsigned short* __restrict__ B,
                     unsigned short* __restrict__ qkv) {
    __shared__ unsigned short As[128 * 64];
    __shared__ unsigned short Bs[128 * 64];
    const int tid = threadIdx.x, w = tid >> 6, l = tid & 63;
    const int g = l >> 4, r16 = l & 15;
    const int m0 = blockIdx.x * 128, n0 = blockIdx.y * 128;
    const int wm = (w >> 1) * 64, wn = (w & 1) * 64;

    f32x4 acc[4][4];
#pragma unroll
    for (int mr = 0; mr < 4; ++mr)
#pragma unroll
        for (int nr = 0; nr < 4; ++nr) acc[mr][nr] = (f32x4){0.f, 0.f, 0.f, 0.f};

    for (int kb = 0; kb < DIM; kb += 64) {
        __syncthreads();
#pragma unroll
        for (int cc = 0; cc < 4; ++cc) {
            int row = w * 32 + cc * 8 + (l >> 3);
            int c = (l & 7) ^ (row & 7);
            gll16(&A[(size_t)(m0 + row) * DIM + kb + c * 8], &As[(size_t)(w * 32 + cc * 8) * 64]);
            gll16(&B[(size_t)(n0 + row) * DIM + kb + c * 8], &Bs[(size_t)(w * 32 + cc * 8) * 64]);
        }
        __syncthreads();
#pragma unroll
        for (int s = 0; s < 2; ++s) {
            bf16x8 af[4], bf[4];
#pragma unroll
            for (int mr = 0; mr < 4; ++mr) {
                int row = wm + mr * 16 + r16;
                int st = (s * 4 + g) ^ (row & 7);
                af[mr] = *(const bf16x8*)&As[row * 64 + st * 8];
            }
#pragma unroll
            for (int nr = 0; nr < 4; ++nr) {
                int row = wn + nr * 16 + r16;
                int st = (s * 4 + g) ^ (row & 7);
                bf[nr] = *(const bf16x8*)&Bs[row * 64 + st * 8];
            }
#pragma unroll
            for (int mr = 0; mr < 4; ++mr)
#pragma unroll
                for (int nr = 0; nr < 4; ++nr)
                    acc[mr][nr] = mfma16(af[mr], bf[nr], acc[mr][nr]);
        }
    }
#pragma unroll
    for (int mr = 0; mr < 4; ++mr)
#pragma unroll
        for (int nr = 0; nr < 4; ++nr) {
            int n = n0 + wn + nr * 16 + r16;
            int h = n >> 8, c = n & 255;
#pragma unroll
            for (int r = 0; r < 4; ++r) {
                int m = m0 + wm + mr * 16 + g * 4 + r;
                qkv[((size_t)h * SEQ + m) * DHEAD + c] = f2b(acc[mr][nr][r]);
            }
        }
}

// ---------------------------------------------------------------------------
// K2: MFMA flash attention, split-K over 2 key halves, KBLK=32, ~53KB LDS.
// grid 512: bid&7 = (head<<1)|half (XCD-pins the K/V stream), bid>>3 = qb.
// 4 waves. R4's proven lane layouts; R5's proven pipeline:
//   barrier1 = vmcnt(0)+s_barrier (drains only K(t), prefetched 1 iter ago)
//   stage V(t) then prefetch K(t+1)
//   QK^T -> in-register softmax (defer-rescale THR=8) -> Ps
//   barrier2 = vmcnt(4)+lgkmcnt(0)+s_barrier (waits V only; K stays in flight)
//   PV
// ---------------------------------------------------------------------------
__global__ __launch_bounds__(256, 2)
void attn_kernel(const unsigned short* __restrict__ qkv,
                 const unsigned short* __restrict__ qkvT,
                 unsigned short* __restrict__ p0,
                 unsigned short* __restrict__ p1,
                 float* __restrict__ ml) {
    __shared__ unsigned short Ks[2][32 * 256];  // 2 x 16KB, row j: st=(c&24)|((c&7)^(j&7))
    __shared__ unsigned short Vt[256 * 32];     // 16KB, row d: st = c ^ (d&3)
    __shared__ unsigned short Ps[64 * 32];      // 4KB,  row q: st = (j>>3) ^ ((q>>2)&3)
    __shared__ float alphaS[64];
    __shared__ float mS[64], lS[64];

    const int tid = threadIdx.x, w = tid >> 6, l = tid & 63;
    const int g = l >> 4, r16 = l & 15;
    const int bid = blockIdx.x;
    const int h = (bid & 7) >> 1, hf = bid & 1;
    const int qb = bid >> 3;
    const unsigned short* __restrict__ qh = qkv + (size_t)h * SEQ * DHEAD;
    const unsigned short* __restrict__ qth = qkvT + (size_t)h * DHEAD * SEQ;
    const int jb0 = hf * (SEQ / 2);
    const int NT = (SEQ / 2) / 32;   // 64 key tiles of 32

    // Q fragments (B-operand): lane q-row = qb*64 + w*16 + r16, d = 32s + 8g + e
    bf16x8 qf[8];
    {
        const unsigned short* qrow = qh + (size_t)(qb * 64 + w * 16 + r16) * DHEAD + g * 8;
#pragma unroll
        for (int s = 0; s < 8; ++s) qf[s] = *(const bf16x8*)(qrow + s * 32);
    }

#define STAGEK(buf, jb)                                                             \
    {                                                                               \
        _Pragma("unroll")                                                           \
        for (int cc = 0; cc < 4; ++cc) {                                            \
            int ch = w * 4 + cc;              /* 1KB chunk = 2 K-rows */            \
            int j = ch * 2 + (l >> 5);                                              \
            int cp = l & 31;                                                        \
            int c = (cp & 24) | ((cp & 7) ^ (j & 7));                               \
            gll16(&qh[(size_t)((jb) + j) * DHEAD + c * 8], &Ks[buf][(size_t)ch * 512]); \
        }                                                                           \
    }
#define STAGEV(jb)                                                                  \
    {                                                                               \
        _Pragma("unroll")                                                           \
        for (int cc = 0; cc < 4; ++cc) {                                            \
            int ch = w * 4 + cc;              /* 1KB chunk = 16 Vt-rows */          \
            int d = ch * 16 + (l >> 2);                                             \
            int c = (l & 3) ^ (d & 3);                                              \
            gll16(&qth[(size_t)d * SEQ + (jb) + c * 8], &Vt[(size_t)ch * 512]);     \
        }                                                                           \
    }

    STAGEK(0, jb0);   // prologue: 4 gll16/wave in flight

    f32x4 Oacc[16];  // [qs*4+dt]: lane holds O[q = qs*16+4g+r][d = w*64+dt*16+r16]
#pragma unroll
    for (int i = 0; i < 16; ++i) Oacc[i] = (f32x4){0.f, 0.f, 0.f, 0.f};
    float mrow = -INFINITY, lrow = 0.f;   // for q-row w*16 + r16 (same across g)

    for (int t = 0; t < NT; ++t) {
        const int cur = t & 1;
        const int jb = jb0 + t * 32;
        const int jbn = jb0 + ((t + 1) & (NT - 1)) * 32;  // wrap keeps vmcnt(4) exact

        // ---- barrier1: K(t) landed; Vt/Ps free for overwrite ----
        __builtin_amdgcn_sched_barrier(0);
        asm volatile("s_waitcnt vmcnt(0)" ::: "memory");
        __builtin_amdgcn_s_barrier();
        __builtin_amdgcn_sched_barrier(0);

        STAGEV(jb);              // 4 gll16 (oldest -> drained at barrier2)
        STAGEK(cur ^ 1, jbn);    // 4 gll16 (stay in flight across barrier2)
        __builtin_amdgcn_sched_barrier(0);

        // ---- S^T = K @ Q^T : lane gets S[q=r16][j = 16jt + 4g + r] ----
        const unsigned short* Kb = &Ks[cur][0];
        f32x4 sacc[2];
#pragma unroll
        for (int jt = 0; jt < 2; ++jt) sacc[jt] = (f32x4){0.f, 0.f, 0.f, 0.f};
        __builtin_amdgcn_s_setprio(1);
#pragma unroll
        for (int s = 0; s < 8; ++s)
#pragma unroll
            for (int jt = 0; jt < 2; ++jt) {
                int j = jt * 16 + r16;
                int c = s * 4 + g;
                int st = (c & 24) | ((c & 7) ^ (j & 7));
                bf16x8 af = *(const bf16x8*)&Kb[j * 256 + st * 8];
                sacc[jt] = mfma16(af, qf[s], sacc[jt]);
            }
        __builtin_amdgcn_s_setprio(0);

        // ---- in-register online softmax, defer-rescale THR=8 ----
        float mx = sacc[0][0];
#pragma unroll
        for (int jt = 0; jt < 2; ++jt)
#pragma unroll
            for (int r = 0; r < 4; ++r) mx = fmaxf(mx, sacc[jt][r]);
        mx = fmaxf(mx, __shfl_xor(mx, 16, 64));
        mx = fmaxf(mx, __shfl_xor(mx, 32, 64));

        float alpha = 1.f;
        if (!__all(mx <= mrow + 8.f)) {
            float mn = fmaxf(mrow, mx);
            alpha = __expf(mrow - mn);
            mrow = mn;
        }

        float rsum = 0.f;
        short4v pf[2];
#pragma unroll
        for (int jt = 0; jt < 2; ++jt)
#pragma unroll
            for (int r = 0; r < 4; ++r) {
                float p = __expf(sacc[jt][r] - mrow);
                rsum += p;
                pf[jt][r] = (short)f2b(p);
            }
        rsum += __shfl_xor(rsum, 16, 64);
        rsum += __shfl_xor(rsum, 32, 64);
        lrow = lrow * alpha + rsum;

        // P -> Ps: row q = w*16+r16; j = 16jt + 4g + {0..3}
#pragma unroll
        for (int jt = 0; jt < 2; ++jt) {
            int st = (2 * jt + (g >> 1)) ^ ((r16 >> 2) & 3);
            *(short4v*)&Ps[(w * 16 + r16) * 32 + st * 8 + (g & 1) * 4] = pf[jt];
        }
        if (g == 0) alphaS[w * 16 + r16] = alpha;

        // ---- barrier2: V landed (counted), Ps/alphaS visible; K in flight ----
        __builtin_amdgcn_sched_barrier(0);
        asm volatile("s_waitcnt vmcnt(4) lgkmcnt(0)" ::: "memory");
        __builtin_amdgcn_s_barrier();
        __builtin_amdgcn_sched_barrier(0);

        // ---- O += P @ V on all 64 q-rows x this wave's 64-wide d-slice ----
        bf16x8 pa[4];
#pragma unroll
        for (int qs = 0; qs < 4; ++qs) {
            int q = qs * 16 + r16;
            int st = g ^ ((q >> 2) & 3);
            pa[qs] = *(const bf16x8*)&Ps[q * 32 + st * 8];
            f32x4 av = *(const f32x4*)&alphaS[qs * 16 + g * 4];
            if (!__all((av[0] == 1.f) & (av[1] == 1.f) & (av[2] == 1.f) & (av[3] == 1.f))) {
#pragma unroll
                for (int dt = 0; dt < 4; ++dt)
#pragma unroll
                    for (int r = 0; r < 4; ++r) Oacc[qs * 4 + dt][r] *= av[r];
            }
        }
        bf16x8 bv[4];
#pragma unroll
        for (int dt = 0; dt < 4; ++dt) {
            int d = w * 64 + dt * 16 + r16;
            int st = g ^ (d & 3);
            bv[dt] = *(const bf16x8*)&Vt[d * 32 + st * 8];
        }
        __builtin_amdgcn_s_setprio(1);
#pragma unroll
        for (int dt = 0; dt < 4; ++dt)
#pragma unroll
            for (int qs = 0; qs < 4; ++qs)
                Oacc[qs * 4 + dt] = mfma16(pa[qs], bv[dt], Oacc[qs * 4 + dt]);
        __builtin_amdgcn_s_setprio(0);
    }
#undef STAGEK
#undef STAGEV

    // drain straggling async ops (wrapped K prefetch) before exit
    asm volatile("s_waitcnt vmcnt(0)" ::: "memory");

    // ---- epilogue: unnormalized partial O (bf16) + per-row (m, l) ----
    if (g == 0) { mS[w * 16 + r16] = mrow; lS[w * 16 + r16] = lrow; }
    __syncthreads();
    unsigned short* po = hf ? p1 : p0;
#pragma unroll
    for (int qs = 0; qs < 4; ++qs)
#pragma unroll
        for (int dt = 0; dt < 4; ++dt) {
            int d = w * 64 + dt * 16 + r16;
#pragma unroll
            for (int r = 0; r < 4; ++r) {
                int q = qb * 64 + qs * 16 + g * 4 + r;
                po[(size_t)q * (NHEADS * DHEAD) + h * DHEAD + d] = f2b(Oacc[qs * 4 + dt][r]);
            }
        }
    if (tid < 64) {
        int q = qb * 64 + tid;
        float* mlq = ml + ((size_t)(hf * NHEADS + h) * SEQ + q) * 2;
        mlq[0] = mS[tid]; mlq[1] = lS[tid];
    }
}

// ---------------------------------------------------------------------------
// K2b: combine the two key-halves:
// out = (e0*acc0 + e1*acc1) / (e0*l0 + e1*l1),  e_i = exp(m_i - max(m0,m1))
// ---------------------------------------------------------------------------
__global__ __launch_bounds__(256)
void combine_kernel(const unsigned short* __restrict__ pa,
                    const unsigned short* __restrict__ pb,
                    const float* __restrict__ ml,
                    unsigned short* __restrict__ zc) {
    size_t t = (size_t)blockIdx.x * 256 + threadIdx.x;
    size_t f = t * 8;
    int q = (int)(f >> 10);
    int h = (int)((f >> 8) & 3);
    const float* ml0 = ml + ((size_t)h * SEQ + q) * 2;
    const float* ml1 = ml + ((size_t)(NHEADS + h) * SEQ + q) * 2;
    float m0 = ml0[0], l0 = ml0[1], m1 = ml1[0], l1 = ml1[1];
    float M = fmaxf(m0, m1);
    float e0 = __expf(m0 - M), e1 = __expf(m1 - M);
    float inv = 1.f / (e0 * l0 + e1 * l1);
    e0 *= inv; e1 *= inv;
    short8v a = *(const short8v*)(pa + f);
    short8v b = *(const short8v*)(pb + f);
    short8v o;
#pragma unroll
    for (int e = 0; e < 8; ++e)
        o[e] = (short)f2b(e0 * b2f((unsigned short)a[e]) + e1 * b2f((unsigned short)b[e]));
    *(short8v*)(zc + f) = o;
}

// ---------------------------------------------------------------------------
// K3: out = zc @ lin_w^T + lin_b  (fp32 out + bias)
// ---------------------------------------------------------------------------
__global__ __launch_bounds__(256)
void out_gemm_kernel(const unsigned short* __restrict__ A,
                     const unsigned short* __restrict__ B,
                     const float* __restrict__ lb, float* __restrict__ out) {
    __shared__ unsigned short As[128 * 64];
    __shared__ unsigned short Bs[128 * 64];
    const int tid = threadIdx.x, w = tid >> 6, l = tid & 63;
    const int g = l >> 4, r16 = l & 15;
    const int m0 = blockIdx.x * 128, n0 = blockIdx.y * 128;
    const int wm = (w >> 1) * 64, wn = (w & 1) * 64;

    f32x4 acc[4][4];
#pragma unroll
    for (int mr = 0; mr < 4; ++mr)
#pragma unroll
        for (int nr = 0; nr < 4; ++nr) acc[mr][nr] = (f32x4){0.f, 0.f, 0.f, 0.f};

    for (int kb = 0; kb < DIM; kb += 64) {
        __syncthreads();
#pragma unroll
        for (int cc = 0; cc < 4; ++cc) {
            int row = w * 32 + cc * 8 + (l >> 3);
            int c = (l & 7) ^ (row & 7);
            gll16(&A[(size_t)(m0 + row) * DIM + kb + c * 8], &As[(size_t)(w * 32 + cc * 8) * 64]);
            gll16(&B[(size_t)(n0 + row) * DIM + kb + c * 8], &Bs[(size_t)(w * 32 + cc * 8) * 64]);
        }
        __syncthreads();
#pragma unroll
        for (int s = 0; s < 2; ++s) {
            bf16x8 af[4], bf[4];
#pragma unroll
            for (int mr = 0; mr < 4; ++mr) {
                int row = wm + mr * 16 + r16;
                int st = (s * 4 + g) ^ (row & 7);
                af[mr] = *(const bf16x8*)&As[row * 64 + st * 8];
            }
#pragma unroll
            for (int nr = 0; nr < 4; ++nr) {
                int row = wn + nr * 16 + r16;
                int st = (s * 4 + g) ^ (row & 7);
                bf[nr] = *(const bf16x8*)&Bs[row * 64 + st * 8];
            }
#pragma unroll
            for (int mr = 0; mr < 4; ++mr)
#pragma unroll
                for (int nr = 0; nr < 4; ++nr)
                    acc[mr][nr] = mfma16(af[mr], bf[nr], acc[mr][nr]);
        }
    }
#pragma unroll
    for (int mr = 0; mr < 4; ++mr)
#pragma unroll
        for (int nr = 0; nr < 4; ++nr) {
            int n = n0 + wn + nr * 16 + r16;
            float bv = lb[n];
#pragma unroll
            for (int r = 0; r < 4; ++r) {
                int m = m0 + wm + mr * 16 + g * 4 + r;
                out[(size_t)m * DIM + n] = acc[mr][nr][r] + bv;
            }
        }
}

// ---------------------------------------------------------------------------
extern "C" void kernel_launch(void* const* d_in, const int* in_sizes, int n_in,
                              void* d_out, int out_size, void* d_ws, size_t ws_size,
                              hipStream_t stream) {
    const float* x  = (const float*)d_in[0];   // [4096,1024]
    const float* Wq = (const float*)d_in[1];   // [4,1024,256]
    const float* lw = (const float*)d_in[2];   // [1024,1024]
    const float* lb = (const float*)d_in[3];   // [1024]
    float* out = (float*)d_out;                // [4096,1024] fp32

    char* wsb = (char*)d_ws;
    unsigned short* qkvb = (unsigned short*)(wsb);                      // [0,8)MB  [4][4096][256]
    unsigned short* qkvT = (unsigned short*)(wsb + ((size_t)8 << 20));  // [8,16)   [4][256][4096]
    unsigned short* xb   = (unsigned short*)(wsb + ((size_t)16 << 20)); // [16,24)  x bf16 -> p0/zc
    unsigned short* p0   = xb;                                          //          (post qkv_gemm)
    unsigned short* WqT  = (unsigned short*)(wsb + ((size_t)24 << 20)); // [24,26)  WqT bf16
    float*          ml   = (float*)(wsb + ((size_t)24 << 20));          //          reused post qkv_gemm
    unsigned short* lwb  = (unsigned short*)(wsb + ((size_t)26 << 20)); // [26,28)  lin_w bf16
    unsigned short* p1   = (unsigned short*)d_out;  // half-1 partial parks in d_out
                                                    // (dead until out_gemm, which runs last)

    conv_kernel<<<4096, 256, 0, stream>>>(x, xb, (SEQ * DIM) / 4);
    conv_kernel<<<1024, 256, 0, stream>>>(lw, lwb, (DIM * DIM) / 4);
    wqt_kernel<<<dim3(16, 4, 4), 256, 0, stream>>>(Wq, WqT);
    qkv_gemm_kernel<<<dim3(SEQ / 128, DIM / 128), 256, 0, stream>>>(xb, WqT, qkvb);
    qkvt_kernel<<<dim3(64, 4, 4), 256, 0, stream>>>(qkvb, qkvT);
    attn_kernel<<<512, 256, 0, stream>>>(qkvb, qkvT, p0, p1, ml);
    combine_kernel<<<(SEQ * DIM / 8) / 256, 256, 0, stream>>>(p0, p1, ml, p0);
    out_gemm_kernel<<<dim3(SEQ / 128, DIM / 128), 256, 0, stream>>>(p0, lwb, lb, out);
}

// Round 8
// 167.863 us; speedup vs baseline: 1.2358x; 1.1630x over previous
//
#include <hip/hip_runtime.h>
#include <math.h>

#define SEQ 4096
#define DIM 1024
#define DHEAD 256
#define NHEADS 4

typedef __attribute__((ext_vector_type(8))) short bf16x8;
typedef __attribute__((ext_vector_type(4))) float f32x4;
typedef __attribute__((ext_vector_type(4))) short short4v;
typedef __attribute__((ext_vector_type(8))) short short8v;

// fp32 -> bf16 round-to-nearest-even, as raw ushort bits
__device__ __forceinline__ unsigned short f2b(float f) {
    union { float f; unsigned u; } v; v.f = f;
    unsigned r = v.u + 0x7FFFu + ((v.u >> 16) & 1u);
    return (unsigned short)(r >> 16);
}
__device__ __forceinline__ float b2f(unsigned short u) {
    union { unsigned u; float f; } v; v.u = ((unsigned)u) << 16;
    return v.f;
}

// async global->LDS, 16B per lane; lds = wave-uniform base, g is per-lane
__device__ __forceinline__ void gll16(const void* g, void* lds) {
    __builtin_amdgcn_global_load_lds(
        (const __attribute__((address_space(1))) unsigned*)g,
        (__attribute__((address_space(3))) unsigned*)lds, 16, 0, 0);
}

__device__ __forceinline__ f32x4 mfma16(bf16x8 a, bf16x8 b, f32x4 c) {
    return __builtin_amdgcn_mfma_f32_16x16x32_bf16(a, b, c, 0, 0, 0);
}

// ---------------------------------------------------------------------------
// convert fp32 -> bf16, n4 float4's
// ---------------------------------------------------------------------------
__global__ __launch_bounds__(256)
void conv_kernel(const float* __restrict__ in, unsigned short* __restrict__ out, int n4) {
    int i = blockIdx.x * 256 + threadIdx.x;
    if (i >= n4) return;
    float4 v = ((const float4*)in)[i];
    short4v o;
    o[0] = (short)f2b(v.x); o[1] = (short)f2b(v.y);
    o[2] = (short)f2b(v.z); o[3] = (short)f2b(v.w);
    *(short4v*)(out + (size_t)i * 4) = o;
}

// ---------------------------------------------------------------------------
// Wq [4][1024][256] fp32 -> WqT [4][256][1024] bf16
// ---------------------------------------------------------------------------
__global__ __launch_bounds__(256)
void wqt_kernel(const float* __restrict__ Wq, unsigned short* __restrict__ WqT) {
    __shared__ unsigned short T[64][72];
    const int tid = threadIdx.x;
    const int h = blockIdx.z;
    const int d0 = blockIdx.x * 64, c0 = blockIdx.y * 64;
#pragma unroll
    for (int it = 0; it < 4; ++it) {
        int f = tid + 256 * it;
        int row = f >> 4, cg = f & 15;
        float4 v = *(const float4*)&Wq[((size_t)(h * DIM + d0 + row)) * DHEAD + c0 + cg * 4];
        T[row][cg * 4 + 0] = f2b(v.x); T[row][cg * 4 + 1] = f2b(v.y);
        T[row][cg * 4 + 2] = f2b(v.z); T[row][cg * 4 + 3] = f2b(v.w);
    }
    __syncthreads();
#pragma unroll
    for (int it = 0; it < 2; ++it) {
        int f = tid + 256 * it;
        int cl = f >> 3, dg = f & 7;
        short8v o;
#pragma unroll
        for (int e = 0; e < 8; ++e) o[e] = (short)T[dg * 8 + e][cl];
        *(short8v*)&WqT[((size_t)(h * DHEAD + c0 + cl)) * DIM + d0 + dg * 8] = o;
    }
}

// ---------------------------------------------------------------------------
// qkv [4][4096][256] bf16 -> qkvT [4][256][4096] bf16
// ---------------------------------------------------------------------------
__global__ __launch_bounds__(256)
void qkvt_kernel(const unsigned short* __restrict__ qkv, unsigned short* __restrict__ qkvT) {
    __shared__ unsigned short T[64][72];
    const int tid = threadIdx.x;
    const int h = blockIdx.z;
    const int r0 = blockIdx.x * 64, c0 = blockIdx.y * 64;
#pragma unroll
    for (int it = 0; it < 2; ++it) {
        int f = tid + 256 * it;
        int row = f >> 3, cg = f & 7;
        short8v v = *(const short8v*)&qkv[((size_t)h * SEQ + r0 + row) * DHEAD + c0 + cg * 8];
#pragma unroll
        for (int e = 0; e < 8; ++e) T[row][cg * 8 + e] = (unsigned short)v[e];
    }
    __syncthreads();
#pragma unroll
    for (int it = 0; it < 2; ++it) {
        int f = tid + 256 * it;
        int cl = f >> 3, rg = f & 7;
        short8v o;
#pragma unroll
        for (int e = 0; e < 8; ++e) o[e] = (short)T[rg * 8 + e][cl];
        *(short8v*)&qkvT[((size_t)h * DHEAD + c0 + cl) * SEQ + r0 + rg * 8] = o;
    }
}

// ---------------------------------------------------------------------------
// K1: qkv = x @ Wq  (bf16 MFMA, BM=BN=128, BK=64, out: qkv bf16 [4][4096][256])
// ---------------------------------------------------------------------------
__global__ __launch_bounds__(256)
void qkv_gemm_kernel(const unsigned short* __restrict__ A,
                     const unsigned short* __restrict__ B,
                     unsigned short* __restrict__ qkv) {
    __shared__ unsigned short As[128 * 64];
    __shared__ unsigned short Bs[128 * 64];
    const int tid = threadIdx.x, w = tid >> 6, l = tid & 63;
    const int g = l >> 4, r16 = l & 15;
    const int m0 = blockIdx.x * 128, n0 = blockIdx.y * 128;
    const int wm = (w >> 1) * 64, wn = (w & 1) * 64;

    f32x4 acc[4][4];
#pragma unroll
    for (int mr = 0; mr < 4; ++mr)
#pragma unroll
        for (int nr = 0; nr < 4; ++nr) acc[mr][nr] = (f32x4){0.f, 0.f, 0.f, 0.f};

    for (int kb = 0; kb < DIM; kb += 64) {
        __syncthreads();
#pragma unroll
        for (int cc = 0; cc < 4; ++cc) {
            int row = w * 32 + cc * 8 + (l >> 3);
            int c = (l & 7) ^ (row & 7);
            gll16(&A[(size_t)(m0 + row) * DIM + kb + c * 8], &As[(size_t)(w * 32 + cc * 8) * 64]);
            gll16(&B[(size_t)(n0 + row) * DIM + kb + c * 8], &Bs[(size_t)(w * 32 + cc * 8) * 64]);
        }
        __syncthreads();
#pragma unroll
        for (int s = 0; s < 2; ++s) {
            bf16x8 af[4], bf[4];
#pragma unroll
            for (int mr = 0; mr < 4; ++mr) {
                int row = wm + mr * 16 + r16;
                int st = (s * 4 + g) ^ (row & 7);
                af[mr] = *(const bf16x8*)&As[row * 64 + st * 8];
            }
#pragma unroll
            for (int nr = 0; nr < 4; ++nr) {
                int row = wn + nr * 16 + r16;
                int st = (s * 4 + g) ^ (row & 7);
                bf[nr] = *(const bf16x8*)&Bs[row * 64 + st * 8];
            }
#pragma unroll
            for (int mr = 0; mr < 4; ++mr)
#pragma unroll
                for (int nr = 0; nr < 4; ++nr)
                    acc[mr][nr] = mfma16(af[mr], bf[nr], acc[mr][nr]);
        }
    }
#pragma unroll
    for (int mr = 0; mr < 4; ++mr)
#pragma unroll
        for (int nr = 0; nr < 4; ++nr) {
            int n = n0 + wn + nr * 16 + r16;
            int h = n >> 8, c = n & 255;
#pragma unroll
            for (int r = 0; r < 4; ++r) {
                int m = m0 + wm + mr * 16 + g * 4 + r;
                qkv[((size_t)h * SEQ + m) * DHEAD + c] = f2b(acc[mr][nr][r]);
            }
        }
}

// ---------------------------------------------------------------------------
// K2: MFMA flash attention. 512 threads / 8 waves, ONE block per CU (144KB
// LDS). grid 256: bid&7 = (head<<1)|half (XCD-pinned), bid>>3 = q-block of
// 128 rows. Wave w owns q-rows [qb*128+w*16, +16) end-to-end.
// Full double-buffer of K and V^T with counted vmcnt:
//   B1: vmcnt(8) (stage(t) landed; stage(t+1) stays in flight) + s_barrier
//   QK^T -> in-register softmax (defer-rescale THR=8, shfl alpha bcast)
//   P -> own-wave Ps (intra-wave lgkmcnt fence, no barrier)
//   PV over own 16 q-rows x all 256 d
//   B2: s_barrier (all waves done with buf[cur]) -> stage(t+2) into buf[cur]
// All MFMA/LDS lane layouts byte-identical to the R4-passing kernel.
// ---------------------------------------------------------------------------
__global__ __launch_bounds__(512, 2)
void attn_kernel(const unsigned short* __restrict__ qkv,
                 const unsigned short* __restrict__ qkvT,
                 unsigned short* __restrict__ p0,
                 unsigned short* __restrict__ p1,
                 float* __restrict__ ml) {
    __shared__ unsigned short Ks[2][64 * 256];  // 2x32KB, row j: st=(c&24)|((c&7)^(j&7))
    __shared__ unsigned short Vt[2][256 * 64];  // 2x32KB, row d: st=c^(d&7)
    __shared__ unsigned short Ps[8][16 * 64];   // 8x2KB,  row q: st=(j>>3)^(q&7)

    const int tid = threadIdx.x, w = tid >> 6, l = tid & 63;
    const int g = l >> 4, r16 = l & 15;
    const int bid = blockIdx.x;
    const int h = (bid & 7) >> 1, hf = bid & 1;
    const int qb = bid >> 3;                     // 0..31, 128 q-rows each
    const unsigned short* __restrict__ qh = qkv + (size_t)h * SEQ * DHEAD;
    const unsigned short* __restrict__ qth = qkvT + (size_t)h * DHEAD * SEQ;
    const int jb0 = hf * (SEQ / 2);
    const int NT = (SEQ / 2) / 64;               // 32 key tiles

    // Q fragments (B-operand): lane q-row = qb*128 + w*16 + r16, d = 32s+8g+e
    bf16x8 qf[8];
    {
        const unsigned short* qrow =
            qh + (size_t)(qb * 128 + w * 16 + r16) * DHEAD + g * 8;
#pragma unroll
        for (int s = 0; s < 8; ++s) qf[s] = *(const bf16x8*)(qrow + s * 32);
    }

#define STAGEK(buf, jb)                                                             \
    {                                                                               \
        _Pragma("unroll")                                                           \
        for (int cc = 0; cc < 4; ++cc) {                                            \
            int ch = w * 4 + cc;              /* 1KB chunk = 2 K-rows */            \
            int j = ch * 2 + (l >> 5);                                              \
            int cp = l & 31;                                                        \
            int c = (cp & 24) | ((cp & 7) ^ (j & 7));                               \
            gll16(&qh[(size_t)((jb) + j) * DHEAD + c * 8], &Ks[buf][(size_t)ch * 512]); \
        }                                                                           \
    }
#define STAGEV(buf, jb)                                                             \
    {                                                                               \
        _Pragma("unroll")                                                           \
        for (int cc = 0; cc < 4; ++cc) {                                            \
            int ch = w * 4 + cc;              /* 1KB chunk = 8 Vt-rows */           \
            int d = ch * 8 + (l >> 3);                                              \
            int c = (l & 7) ^ (d & 7);                                              \
            gll16(&qth[(size_t)d * SEQ + (jb) + c * 8], &Vt[buf][(size_t)ch * 512]); \
        }                                                                           \
    }

    // prologue: tiles 0 and 1 in flight (16 gll16/wave)
    STAGEK(0, jb0); STAGEV(0, jb0);
    STAGEK(1, jb0 + 64); STAGEV(1, jb0 + 64);

    f32x4 Oacc[16];  // [dt]: lane holds O[q = w*16 + 4g + r][d = dt*16 + r16]
#pragma unroll
    for (int i = 0; i < 16; ++i) Oacc[i] = (f32x4){0.f, 0.f, 0.f, 0.f};
    float mrow = -INFINITY, lrow = 0.f;   // for q-row w*16 + r16 (same across g)

    for (int t = 0; t < NT; ++t) {
        const int cur = t & 1;

        // ---- B1: stage(t) landed; stage(t+1) stays in flight ----
        __builtin_amdgcn_sched_barrier(0);
        if (t + 1 < NT) { asm volatile("s_waitcnt vmcnt(8)" ::: "memory"); }
        else            { asm volatile("s_waitcnt vmcnt(0)" ::: "memory"); }
        __builtin_amdgcn_s_barrier();
        __builtin_amdgcn_sched_barrier(0);

        // ---- S^T = K @ Q^T : lane gets S[q=r16][j = 16jt + 4g + r] ----
        const unsigned short* Kb = &Ks[cur][0];
        f32x4 sacc[4];
#pragma unroll
        for (int jt = 0; jt < 4; ++jt) sacc[jt] = (f32x4){0.f, 0.f, 0.f, 0.f};
        __builtin_amdgcn_s_setprio(1);
#pragma unroll
        for (int s = 0; s < 8; ++s)
#pragma unroll
            for (int jt = 0; jt < 4; ++jt) {
                int j = jt * 16 + r16;
                int c = s * 4 + g;
                int st = (c & 24) | ((c & 7) ^ (j & 7));
                bf16x8 af = *(const bf16x8*)&Kb[j * 256 + st * 8];
                sacc[jt] = mfma16(af, qf[s], sacc[jt]);
            }
        __builtin_amdgcn_s_setprio(0);

        // ---- in-register online softmax, defer-rescale THR=8 ----
        float mx = sacc[0][0];
#pragma unroll
        for (int jt = 0; jt < 4; ++jt)
#pragma unroll
            for (int r = 0; r < 4; ++r) mx = fmaxf(mx, sacc[jt][r]);
        mx = fmaxf(mx, __shfl_xor(mx, 16, 64));
        mx = fmaxf(mx, __shfl_xor(mx, 32, 64));

        const bool needr = !__all(mx <= mrow + 8.f);
        float alpha = 1.f;
        if (needr) {
            float mn = fmaxf(mrow, mx);
            alpha = __expf(mrow - mn);
            mrow = mn;
        }

        float rsum = 0.f;
        short4v pf[4];
#pragma unroll
        for (int jt = 0; jt < 4; ++jt)
#pragma unroll
            for (int r = 0; r < 4; ++r) {
                float p = __expf(sacc[jt][r] - mrow);
                rsum += p;
                pf[jt][r] = (short)f2b(p);
            }
        rsum += __shfl_xor(rsum, 16, 64);
        rsum += __shfl_xor(rsum, 32, 64);
        lrow = lrow * alpha + rsum;

        // P -> own-wave Ps: row q=r16, j = 16jt + 4g + {0..3}
#pragma unroll
        for (int jt = 0; jt < 4; ++jt) {
            int st = (2 * jt + (g >> 1)) ^ (r16 & 7);
            *(short4v*)&Ps[w][r16 * 64 + st * 8 + (g & 1) * 4] = pf[jt];
        }

        // O rescale: alpha for q=4g+r fetched from lane (4g+r) (uniform over g)
        if (needr) {
            float av[4];
#pragma unroll
            for (int r = 0; r < 4; ++r) av[r] = __shfl(alpha, 4 * g + r, 64);
#pragma unroll
            for (int dt = 0; dt < 16; ++dt)
#pragma unroll
                for (int r = 0; r < 4; ++r) Oacc[dt][r] *= av[r];
        }

        // ---- intra-wave fence: own Ps writes visible to own reads ----
        asm volatile("s_waitcnt lgkmcnt(0)" ::: "memory");
        __builtin_amdgcn_sched_barrier(0);

        // ---- PA frags: A[q=r16][k=j = 32s2 + 8g + e] from own Ps ----
        bf16x8 pa[2];
#pragma unroll
        for (int s2 = 0; s2 < 2; ++s2) {
            int st = (4 * s2 + g) ^ (r16 & 7);
            pa[s2] = *(const bf16x8*)&Ps[w][r16 * 64 + st * 8];
        }

        // ---- O += P @ V : own 16 q-rows x all 256 d ----
        const unsigned short* Vb = &Vt[cur][0];
        __builtin_amdgcn_s_setprio(1);
#pragma unroll
        for (int dt = 0; dt < 16; ++dt) {
            int d = dt * 16 + r16;
#pragma unroll
            for (int s2 = 0; s2 < 2; ++s2) {
                int st = (4 * s2 + g) ^ (d & 7);
                bf16x8 bv = *(const bf16x8*)&Vb[d * 64 + st * 8];
                Oacc[dt] = mfma16(pa[s2], bv, Oacc[dt]);
            }
        }
        __builtin_amdgcn_s_setprio(0);

        // ---- B2: all waves done with buf[cur] -> restage it for t+2 ----
        __builtin_amdgcn_sched_barrier(0);
        __builtin_amdgcn_s_barrier();
        __builtin_amdgcn_sched_barrier(0);
        if (t + 2 < NT) {
            const int jb2 = jb0 + (t + 2) * 64;
            STAGEK(cur, jb2); STAGEV(cur, jb2);
        }
        __builtin_amdgcn_sched_barrier(0);
    }
#undef STAGEK
#undef STAGEV

    // ---- epilogue: unnormalized partial O (bf16) + per-row (m, l) ----
    unsigned short* po = hf ? p1 : p0;
#pragma unroll
    for (int dt = 0; dt < 16; ++dt) {
        int d = dt * 16 + r16;
#pragma unroll
        for (int r = 0; r < 4; ++r) {
            int q = qb * 128 + w * 16 + 4 * g + r;
            po[(size_t)q * (NHEADS * DHEAD) + h * DHEAD + d] = f2b(Oacc[dt][r]);
        }
    }
    if (g == 0) {
        int q = qb * 128 + w * 16 + r16;
        float* mlq = ml + ((size_t)(hf * NHEADS + h) * SEQ + q) * 2;
        mlq[0] = mrow; mlq[1] = lrow;
    }
}

// ---------------------------------------------------------------------------
// K2b: combine the two key-halves:
// out = (e0*acc0 + e1*acc1) / (e0*l0 + e1*l1),  e_i = exp(m_i - max(m0,m1))
// ---------------------------------------------------------------------------
__global__ __launch_bounds__(256)
void combine_kernel(const unsigned short* __restrict__ pa,
                    const unsigned short* __restrict__ pb,
                    const float* __restrict__ ml,
                    unsigned short* __restrict__ zc) {
    size_t t = (size_t)blockIdx.x * 256 + threadIdx.x;
    size_t f = t * 8;
    int q = (int)(f >> 10);
    int h = (int)((f >> 8) & 3);
    const float* ml0 = ml + ((size_t)h * SEQ + q) * 2;
    const float* ml1 = ml + ((size_t)(NHEADS + h) * SEQ + q) * 2;
    float m0 = ml0[0], l0 = ml0[1], m1 = ml1[0], l1 = ml1[1];
    float M = fmaxf(m0, m1);
    float e0 = __expf(m0 - M), e1 = __expf(m1 - M);
    float inv = 1.f / (e0 * l0 + e1 * l1);
    e0 *= inv; e1 *= inv;
    short8v a = *(const short8v*)(pa + f);
    short8v b = *(const short8v*)(pb + f);
    short8v o;
#pragma unroll
    for (int e = 0; e < 8; ++e)
        o[e] = (short)f2b(e0 * b2f((unsigned short)a[e]) + e1 * b2f((unsigned short)b[e]));
    *(short8v*)(zc + f) = o;
}

// ---------------------------------------------------------------------------
// K3: out = zc @ lin_w^T + lin_b  (fp32 out + bias)
// ---------------------------------------------------------------------------
__global__ __launch_bounds__(256)
void out_gemm_kernel(const unsigned short* __restrict__ A,
                     const unsigned short* __restrict__ B,
                     const float* __restrict__ lb, float* __restrict__ out) {
    __shared__ unsigned short As[128 * 64];
    __shared__ unsigned short Bs[128 * 64];
    const int tid = threadIdx.x, w = tid >> 6, l = tid & 63;
    const int g = l >> 4, r16 = l & 15;
    const int m0 = blockIdx.x * 128, n0 = blockIdx.y * 128;
    const int wm = (w >> 1) * 64, wn = (w & 1) * 64;

    f32x4 acc[4][4];
#pragma unroll
    for (int mr = 0; mr < 4; ++mr)
#pragma unroll
        for (int nr = 0; nr < 4; ++nr) acc[mr][nr] = (f32x4){0.f, 0.f, 0.f, 0.f};

    for (int kb = 0; kb < DIM; kb += 64) {
        __syncthreads();
#pragma unroll
        for (int cc = 0; cc < 4; ++cc) {
            int row = w * 32 + cc * 8 + (l >> 3);
            int c = (l & 7) ^ (row & 7);
            gll16(&A[(size_t)(m0 + row) * DIM + kb + c * 8], &As[(size_t)(w * 32 + cc * 8) * 64]);
            gll16(&B[(size_t)(n0 + row) * DIM + kb + c * 8], &Bs[(size_t)(w * 32 + cc * 8) * 64]);
        }
        __syncthreads();
#pragma unroll
        for (int s = 0; s < 2; ++s) {
            bf16x8 af[4], bf[4];
#pragma unroll
            for (int mr = 0; mr < 4; ++mr) {
                int row = wm + mr * 16 + r16;
                int st = (s * 4 + g) ^ (row & 7);
                af[mr] = *(const bf16x8*)&As[row * 64 + st * 8];
            }
#pragma unroll
            for (int nr = 0; nr < 4; ++nr) {
                int row = wn + nr * 16 + r16;
                int st = (s * 4 + g) ^ (row & 7);
                bf[nr] = *(const bf16x8*)&Bs[row * 64 + st * 8];
            }
#pragma unroll
            for (int mr = 0; mr < 4; ++mr)
#pragma unroll
                for (int nr = 0; nr < 4; ++nr)
                    acc[mr][nr] = mfma16(af[mr], bf[nr], acc[mr][nr]);
        }
    }
#pragma unroll
    for (int mr = 0; mr < 4; ++mr)
#pragma unroll
        for (int nr = 0; nr < 4; ++nr) {
            int n = n0 + wn + nr * 16 + r16;
            float bv = lb[n];
#pragma unroll
            for (int r = 0; r < 4; ++r) {
                int m = m0 + wm + mr * 16 + g * 4 + r;
                out[(size_t)m * DIM + n] = acc[mr][nr][r] + bv;
            }
        }
}

// ---------------------------------------------------------------------------
extern "C" void kernel_launch(void* const* d_in, const int* in_sizes, int n_in,
                              void* d_out, int out_size, void* d_ws, size_t ws_size,
                              hipStream_t stream) {
    const float* x  = (const float*)d_in[0];   // [4096,1024]
    const float* Wq = (const float*)d_in[1];   // [4,1024,256]
    const float* lw = (const float*)d_in[2];   // [1024,1024]
    const float* lb = (const float*)d_in[3];   // [1024]
    float* out = (float*)d_out;                // [4096,1024] fp32

    char* wsb = (char*)d_ws;
    unsigned short* qkvb = (unsigned short*)(wsb);                      // [0,8)MB  [4][4096][256]
    unsigned short* qkvT = (unsigned short*)(wsb + ((size_t)8 << 20));  // [8,16)   [4][256][4096]
    unsigned short* xb   = (unsigned short*)(wsb + ((size_t)16 << 20)); // [16,24)  x bf16 -> p0/zc
    unsigned short* p0   = xb;                                          //          (post qkv_gemm)
    unsigned short* WqT  = (unsigned short*)(wsb + ((size_t)24 << 20)); // [24,26)  WqT bf16
    float*          ml   = (float*)(wsb + ((size_t)24 << 20));          //          reused post qkv_gemm
    unsigned short* lwb  = (unsigned short*)(wsb + ((size_t)26 << 20)); // [26,28)  lin_w bf16
    unsigned short* p1   = (unsigned short*)d_out;  // half-1 partial parks in d_out
                                                    // (dead until out_gemm, which runs last)

    conv_kernel<<<4096, 256, 0, stream>>>(x, xb, (SEQ * DIM) / 4);
    conv_kernel<<<1024, 256, 0, stream>>>(lw, lwb, (DIM * DIM) / 4);
    wqt_kernel<<<dim3(16, 4, 4), 256, 0, stream>>>(Wq, WqT);
    qkv_gemm_kernel<<<dim3(SEQ / 128, DIM / 128), 256, 0, stream>>>(xb, WqT, qkvb);
    qkvt_kernel<<<dim3(64, 4, 4), 256, 0, stream>>>(qkvb, qkvT);
    attn_kernel<<<256, 512, 0, stream>>>(qkvb, qkvT, p0, p1, ml);
    combine_kernel<<<(SEQ * DIM / 8) / 256, 256, 0, stream>>>(p0, p1, ml, p0);
    out_gemm_kernel<<<dim3(SEQ / 128, DIM / 128), 256, 0, stream>>>(p0, lwb, lb, out);
}